// Round 1
// baseline (49.498 us; speedup 1.0000x reference)
//
#include <hip/hip_runtime.h>
#include <math.h>

// Problem constants (B=256, N=32, D=D1=128, R=O=8)
#define NPAIR 64          // R*O distinct matrices
#define MAXP 512          // max rows per pair (true max ~210; safety margin)
#define TOTAL_ROWS 10240  // B*R centers + B*N neighbors
#define NCENTER 2048      // B*R

// ws layout (ints): [0,64) per-pair cursors; [64, 64+64*512) per-pair row lists.
// Needs 64*4 + 64*512*4 = 131328 bytes of d_ws.

__global__ void build_kernel(const int* __restrict__ center_o,
                             const int* __restrict__ s_types,
                             const int* __restrict__ o_types,
                             int* __restrict__ ws) {
    int id = blockIdx.x * 256 + threadIdx.x;
    if (id >= TOTAL_ROWS) return;
    int p;
    if (id < NCENTER) {
        // center row: id = b*8 + r ; out row = id ; pair = r*8 + center_o[b]
        int bi = id >> 3;
        int r = id & 7;
        p = r * 8 + center_o[bi];
    } else {
        int nid = id - NCENTER;                 // = b*32 + n
        int s = s_types[nid]; if (s < 0) s = 0;
        int o = o_types[nid]; if (o < 0) o = 0;
        p = s * 8 + o;
    }
    int slot = atomicAdd(&ws[p], 1);
    if (slot < MAXP) ws[NPAIR + p * MAXP + slot] = id;
}

__device__ __forceinline__ float gelu_f(float v) {
    // exact gelu: x * 0.5 * (1 + erf(x/sqrt(2)))
    return 0.5f * v * (1.0f + erff(v * 0.70710678118654752f));
}

__global__ __launch_bounds__(256, 2) void gemm_kernel(
    const float* __restrict__ center_h,
    const float* __restrict__ raw_neighbors,
    const float* __restrict__ Mg,
    const float* __restrict__ bias,
    const int* __restrict__ ws,
    float* __restrict__ out) {
    __shared__ float Ms[128 * 128];  // 64 KiB: one (D x D1) matrix

    const int p  = blockIdx.x >> 3;  // pair id 0..63
    const int rs = blockIdx.x & 7;   // row slice 0..7

    // Stage M[p] (64KB) into LDS with float4 loads: 4096 float4 / 256 threads.
    const float4* src = (const float4*)(Mg + p * (128 * 128));
    float4* dst = (float4*)Ms;
    #pragma unroll
    for (int i = 0; i < 16; ++i) dst[threadIdx.x + i * 256] = src[threadIdx.x + i * 256];

    int cnt = ws[p];
    if (cnt > MAXP) cnt = MAXP;
    __syncthreads();

    const int wave = threadIdx.x >> 6;
    const int lane = threadIdx.x & 63;
    const int* myperm = ws + NPAIR + p * MAXP;

    // This block handles global list positions i = rs + 8*j, j in [0, m)
    const int m = (cnt > rs) ? ((cnt - rs + 7) >> 3) : 0;

    const float2 bv = *(const float2*)(bias + p * 128 + lane * 2);
    float2* out2 = (float2*)out;

    for (int j0 = wave * 4; j0 < m; j0 += 16) {
        // 4 rows per wave-group; readfirstlane => uniform (SGPR) row ids
        int id0 = __builtin_amdgcn_readfirstlane(myperm[rs + 8 * j0]);
        int id1 = (j0 + 1 < m) ? __builtin_amdgcn_readfirstlane(myperm[rs + 8 * (j0 + 1)]) : id0;
        int id2 = (j0 + 2 < m) ? __builtin_amdgcn_readfirstlane(myperm[rs + 8 * (j0 + 2)]) : id0;
        int id3 = (j0 + 3 < m) ? __builtin_amdgcn_readfirstlane(myperm[rs + 8 * (j0 + 3)]) : id0;

        const float* xp0 = (id0 < NCENTER) ? (center_h + (id0 >> 3) * 128)
                                           : (raw_neighbors + (id0 - NCENTER) * 128);
        const float* xp1 = (id1 < NCENTER) ? (center_h + (id1 >> 3) * 128)
                                           : (raw_neighbors + (id1 - NCENTER) * 128);
        const float* xp2 = (id2 < NCENTER) ? (center_h + (id2 >> 3) * 128)
                                           : (raw_neighbors + (id2 - NCENTER) * 128);
        const float* xp3 = (id3 < NCENTER) ? (center_h + (id3 >> 3) * 128)
                                           : (raw_neighbors + (id3 - NCENTER) * 128);

        float2 a0 = bv, a1 = bv, a2 = bv, a3 = bv;

        #pragma unroll 8
        for (int d = 0; d < 128; ++d) {
            const float2 mv = *(const float2*)(Ms + d * 128 + lane * 2);
            const float x0 = xp0[d];
            const float x1 = xp1[d];
            const float x2 = xp2[d];
            const float x3 = xp3[d];
            a0.x = fmaf(x0, mv.x, a0.x); a0.y = fmaf(x0, mv.y, a0.y);
            a1.x = fmaf(x1, mv.x, a1.x); a1.y = fmaf(x1, mv.y, a1.y);
            a2.x = fmaf(x2, mv.x, a2.x); a2.y = fmaf(x2, mv.y, a2.y);
            a3.x = fmaf(x3, mv.x, a3.x); a3.y = fmaf(x3, mv.y, a3.y);
        }

        // out row index == id (centers occupy [0,2048) rows, neighbors follow)
        {
            float2 r; r.x = gelu_f(a0.x); r.y = gelu_f(a0.y);
            out2[id0 * 64 + lane] = r;
        }
        if (j0 + 1 < m) { float2 r; r.x = gelu_f(a1.x); r.y = gelu_f(a1.y); out2[id1 * 64 + lane] = r; }
        if (j0 + 2 < m) { float2 r; r.x = gelu_f(a2.x); r.y = gelu_f(a2.y); out2[id2 * 64 + lane] = r; }
        if (j0 + 3 < m) { float2 r; r.x = gelu_f(a3.x); r.y = gelu_f(a3.y); out2[id3 * 64 + lane] = r; }
    }
}

extern "C" void kernel_launch(void* const* d_in, const int* in_sizes, int n_in,
                              void* d_out, int out_size, void* d_ws, size_t ws_size,
                              hipStream_t stream) {
    const float* center_h      = (const float*)d_in[0];
    const float* raw_neighbors = (const float*)d_in[1];
    const float* M             = (const float*)d_in[2];
    const float* bias          = (const float*)d_in[3];
    const int*   center_o      = (const int*)d_in[4];
    const int*   s_types       = (const int*)d_in[5];
    const int*   o_types       = (const int*)d_in[6];
    float* out = (float*)d_out;
    int* ws = (int*)d_ws;

    // zero the 64 per-pair cursors (graph-capture-safe async memset)
    hipMemsetAsync(ws, 0, NPAIR * sizeof(int), stream);
    build_kernel<<<dim3((TOTAL_ROWS + 255) / 256), dim3(256), 0, stream>>>(
        center_o, s_types, o_types, ws);
    gemm_kernel<<<dim3(NPAIR * 8), dim3(256), 0, stream>>>(
        center_h, raw_neighbors, M, bias, ws, out);
}

// Round 2
// 37.383 us; speedup vs baseline: 1.3241x; 1.3241x over previous
//
#include <hip/hip_runtime.h>
#include <math.h>

// Problem constants (B=256, N=32, D=D1=128, R=O=8)
#define NPAIR 64          // R*O distinct matrices
#define MAXP 512          // max rows per pair (true max ~210; safety margin)
#define TOTAL_ROWS 10240  // B*R centers + B*N neighbors
#define NCENTER 2048      // B*R

// ws layout (ints): [0,64) per-pair counts; [64, 64+64*512) per-pair row lists.
// Needs 64*4 + 64*512*4 = 131328 bytes of d_ws.

// Single workgroup: zero cursors in LDS, bin all 10240 rows via LDS atomics,
// publish counts to global at the end. No hipMemsetAsync needed (the in-graph
// fillBufferAligned dispatch was ~39us/replay — 80% of round-1 runtime).
__global__ __launch_bounds__(1024) void build_kernel(
    const int* __restrict__ center_o,
    const int* __restrict__ s_types,
    const int* __restrict__ o_types,
    int* __restrict__ ws) {
    __shared__ int cur[NPAIR];
    const int t = threadIdx.x;
    if (t < NPAIR) cur[t] = 0;
    __syncthreads();
    #pragma unroll
    for (int k = 0; k < TOTAL_ROWS / 1024; ++k) {
        const int id = t + k * 1024;
        int p;
        if (id < NCENTER) {
            // center row: id = b*8 + r ; pair = r*8 + center_o[b]
            const int bi = id >> 3;
            const int r = id & 7;
            p = r * 8 + center_o[bi];
        } else {
            const int nid = id - NCENTER;       // = b*32 + n
            int s = s_types[nid]; if (s < 0) s = 0;
            int o = o_types[nid]; if (o < 0) o = 0;
            p = s * 8 + o;
        }
        const int slot = atomicAdd(&cur[p], 1);
        if (slot < MAXP) ws[NPAIR + p * MAXP + slot] = id;
    }
    __syncthreads();
    if (t < NPAIR) ws[t] = cur[t];
}

__device__ __forceinline__ float gelu_f(float v) {
    // exact gelu: x * 0.5 * (1 + erf(x/sqrt(2)))
    return 0.5f * v * (1.0f + erff(v * 0.70710678118654752f));
}

__global__ __launch_bounds__(256, 2) void gemm_kernel(
    const float* __restrict__ center_h,
    const float* __restrict__ raw_neighbors,
    const float* __restrict__ Mg,
    const float* __restrict__ bias,
    const int* __restrict__ ws,
    float* __restrict__ out) {
    __shared__ float Ms[128 * 128];  // 64 KiB: one (D x D1) matrix

    const int p  = blockIdx.x >> 3;  // pair id 0..63
    const int rs = blockIdx.x & 7;   // row slice 0..7

    // Stage M[p] (64KB) into LDS with float4 loads: 4096 float4 / 256 threads.
    const float4* src = (const float4*)(Mg + p * (128 * 128));
    float4* dst = (float4*)Ms;
    #pragma unroll
    for (int i = 0; i < 16; ++i) dst[threadIdx.x + i * 256] = src[threadIdx.x + i * 256];

    int cnt = ws[p];
    if (cnt > MAXP) cnt = MAXP;
    __syncthreads();

    const int wave = threadIdx.x >> 6;
    const int lane = threadIdx.x & 63;
    const int* myperm = ws + NPAIR + p * MAXP;

    // This block handles global list positions i = rs + 8*j, j in [0, m)
    const int m = (cnt > rs) ? ((cnt - rs + 7) >> 3) : 0;

    const float2 bv = *(const float2*)(bias + p * 128 + lane * 2);
    float2* out2 = (float2*)out;

    for (int j0 = wave * 4; j0 < m; j0 += 16) {
        // 4 rows per wave-group; readfirstlane => uniform (SGPR) row ids
        int id0 = __builtin_amdgcn_readfirstlane(myperm[rs + 8 * j0]);
        int id1 = (j0 + 1 < m) ? __builtin_amdgcn_readfirstlane(myperm[rs + 8 * (j0 + 1)]) : id0;
        int id2 = (j0 + 2 < m) ? __builtin_amdgcn_readfirstlane(myperm[rs + 8 * (j0 + 2)]) : id0;
        int id3 = (j0 + 3 < m) ? __builtin_amdgcn_readfirstlane(myperm[rs + 8 * (j0 + 3)]) : id0;

        const float* xp0 = (id0 < NCENTER) ? (center_h + (id0 >> 3) * 128)
                                           : (raw_neighbors + (id0 - NCENTER) * 128);
        const float* xp1 = (id1 < NCENTER) ? (center_h + (id1 >> 3) * 128)
                                           : (raw_neighbors + (id1 - NCENTER) * 128);
        const float* xp2 = (id2 < NCENTER) ? (center_h + (id2 >> 3) * 128)
                                           : (raw_neighbors + (id2 - NCENTER) * 128);
        const float* xp3 = (id3 < NCENTER) ? (center_h + (id3 >> 3) * 128)
                                           : (raw_neighbors + (id3 - NCENTER) * 128);

        float2 a0 = bv, a1 = bv, a2 = bv, a3 = bv;

        #pragma unroll 8
        for (int d = 0; d < 128; ++d) {
            const float2 mv = *(const float2*)(Ms + d * 128 + lane * 2);
            const float x0 = xp0[d];
            const float x1 = xp1[d];
            const float x2 = xp2[d];
            const float x3 = xp3[d];
            a0.x = fmaf(x0, mv.x, a0.x); a0.y = fmaf(x0, mv.y, a0.y);
            a1.x = fmaf(x1, mv.x, a1.x); a1.y = fmaf(x1, mv.y, a1.y);
            a2.x = fmaf(x2, mv.x, a2.x); a2.y = fmaf(x2, mv.y, a2.y);
            a3.x = fmaf(x3, mv.x, a3.x); a3.y = fmaf(x3, mv.y, a3.y);
        }

        // out row index == id (centers occupy [0,2048) rows, neighbors follow)
        {
            float2 r; r.x = gelu_f(a0.x); r.y = gelu_f(a0.y);
            out2[id0 * 64 + lane] = r;
        }
        if (j0 + 1 < m) { float2 r; r.x = gelu_f(a1.x); r.y = gelu_f(a1.y); out2[id1 * 64 + lane] = r; }
        if (j0 + 2 < m) { float2 r; r.x = gelu_f(a2.x); r.y = gelu_f(a2.y); out2[id2 * 64 + lane] = r; }
        if (j0 + 3 < m) { float2 r; r.x = gelu_f(a3.x); r.y = gelu_f(a3.y); out2[id3 * 64 + lane] = r; }
    }
}

extern "C" void kernel_launch(void* const* d_in, const int* in_sizes, int n_in,
                              void* d_out, int out_size, void* d_ws, size_t ws_size,
                              hipStream_t stream) {
    const float* center_h      = (const float*)d_in[0];
    const float* raw_neighbors = (const float*)d_in[1];
    const float* M             = (const float*)d_in[2];
    const float* bias          = (const float*)d_in[3];
    const int*   center_o      = (const int*)d_in[4];
    const int*   s_types       = (const int*)d_in[5];
    const int*   o_types       = (const int*)d_in[6];
    float* out = (float*)d_out;
    int* ws = (int*)d_ws;

    build_kernel<<<dim3(1), dim3(1024), 0, stream>>>(center_o, s_types, o_types, ws);
    gemm_kernel<<<dim3(NPAIR * 8), dim3(256), 0, stream>>>(
        center_h, raw_neighbors, M, bias, ws, out);
}

// Round 3
// 25.964 us; speedup vs baseline: 1.9064x; 1.4398x over previous
//
#include <hip/hip_runtime.h>
#include <math.h>

// Problem constants (B=256, N=32, D=D1=128, R=O=8)
#define NPAIR 64
#define NCENTER 2048     // B*R center rows
#define NNEIGH 8192      // B*N neighbor rows
#define LISTCAP 256      // per-wave sublist cap (expected max ~80)

__device__ __forceinline__ float gelu_f(float v) {
    // exact gelu: x * 0.5 * (1 + erf(x/sqrt(2)))
    return 0.5f * v * (1.0f + erff(v * 0.70710678118654752f));
}

// One dispatch. 512 blocks = 64 pairs x 8 slices. Each block:
//  A) issues its scan loads (regs), then async-stages M[pair] (64KB) to LDS
//  B) ballot-compacts its pair's row ids into 4 per-wave LDS sublists
//     (deterministic: no atomics, fixed wave->id mapping, in-order prefix)
//  C) processes list positions slice+8*j: 4 rows/wave-group, float4 cols,
//     half-wave row split, 8 fp32 FMA per d-step.
__global__ __launch_bounds__(256, 2) void fused_kernel(
    const float* __restrict__ center_h,
    const float* __restrict__ raw_neighbors,
    const float* __restrict__ Mg,
    const float* __restrict__ bias,
    const int* __restrict__ center_o,
    const int* __restrict__ s_types,
    const int* __restrict__ o_types,
    float* __restrict__ out)
{
    __shared__ float Ms[128 * 128];   // 64 KiB
    __shared__ int  list[4 * LISTCAP];
    __shared__ int  cnts[4];

    const int t     = threadIdx.x;
    const int wave  = t >> 6;
    const int lane  = t & 63;
    const int pair  = blockIdx.x >> 3;   // 0..63
    const int slice = blockIdx.x & 7;    // 0..7
    const int r0 = pair >> 3, o0 = pair & 7;

    // --- A1: scan loads first (so their vmcnt retire doesn't wait on staging)
    const int my_co = center_o[wave * 64 + lane];      // b = wave*64+lane, covers 0..255
    int4 sv[8], ov[8];
    const int4* s4 = (const int4*)s_types;
    const int4* o4 = (const int4*)o_types;
    #pragma unroll
    for (int k = 0; k < 8; ++k) {
        const int idx4 = wave * 64 + lane + k * 256;   // covers 0..2047 (=8192/4)
        sv[k] = s4[idx4];
        ov[k] = o4[idx4];
    }

    // --- A2: async-stage M[pair] into LDS (16B global_load_lds, linear dest)
    const float* src = Mg + pair * 16384;
    #pragma unroll
    for (int i = 0; i < 16; ++i) {
        const int off = (t + i * 256) * 4;             // float index; *16B linear in lane
        __builtin_amdgcn_global_load_lds(
            (const __attribute__((address_space(1))) void*)(src + off),
            (__attribute__((address_space(3))) void*)(&Ms[off]),
            16, 0, 0);
    }

    // --- B: ballot compaction into per-wave sublists (deterministic order)
    int cw = 0;
    {
        const bool match = (my_co == o0);
        const unsigned long long mk = __ballot(match);
        if (match) {
            const int pos = cw + __popcll(mk & ((1ull << lane) - 1));
            if (pos < LISTCAP) list[wave * LISTCAP + pos] = (wave * 64 + lane) * 8 + r0;
        }
        cw += __popcll(mk);
        if (cw > LISTCAP) cw = LISTCAP;
    }
    #pragma unroll
    for (int k = 0; k < 8; ++k) {
        const int base_nid = (wave * 64 + lane + k * 256) * 4;
        const int ss[4] = { sv[k].x, sv[k].y, sv[k].z, sv[k].w };
        const int oo[4] = { ov[k].x, ov[k].y, ov[k].z, ov[k].w };
        #pragma unroll
        for (int j = 0; j < 4; ++j) {
            const int s = ss[j] < 0 ? 0 : ss[j];
            const int o = oo[j] < 0 ? 0 : oo[j];
            const bool match = (s == r0) & (o == o0);
            const unsigned long long mk = __ballot(match);
            if (match) {
                const int pos = cw + __popcll(mk & ((1ull << lane) - 1));
                if (pos < LISTCAP) list[wave * LISTCAP + pos] = NCENTER + base_nid + j;
            }
            cw += __popcll(mk);
            if (cw > LISTCAP) cw = LISTCAP;
        }
    }
    if (lane == 0) cnts[wave] = cw;
    __syncthreads();   // lists visible; vmcnt drained => M fully staged

    // --- C: grouped GEMV. positions idx = slice + 8*jj, jj in [0,m)
    const int c0 = cnts[0], c1 = cnts[1], c2 = cnts[2];
    const int cnt = c0 + c1 + c2 + cnts[3];
    const int m = (cnt > slice) ? ((cnt - slice + 7) >> 3) : 0;

    const int cl   = (lane & 31) * 4;     // my 4 columns
    const int half = lane >> 5;           // row-pair selector
    const float4 bv = *(const float4*)(bias + pair * 128 + cl);
    float4* out4 = (float4*)out;

    for (int g = wave; g * 4 < m; g += 4) {
        int id0, id1, id2, id3;
        {
            int idsv[4];
            #pragma unroll
            for (int e = 0; e < 4; ++e) {
                const int jj = g * 4 + e;
                if (jj < m) {
                    int a = slice + 8 * jj, sw = 0;
                    if (a >= c0) { a -= c0; sw = 1;
                        if (a >= c1) { a -= c1; sw = 2;
                            if (a >= c2) { a -= c2; sw = 3; } } }
                    idsv[e] = list[sw * LISTCAP + a];   // uniform addr => broadcast
                } else idsv[e] = idsv[0];
            }
            id0 = idsv[0]; id1 = idsv[1]; id2 = idsv[2]; id3 = idsv[3];
        }
        // half 0 -> rows id0,id1 ; half 1 -> rows id2,id3  (static select, no scratch)
        const int iA = half ? id2 : id0;
        const int iB = half ? id3 : id1;
        const float* xA = (iA < NCENTER) ? center_h + (iA >> 3) * 128
                                         : raw_neighbors + (iA - NCENTER) * 128;
        const float* xB = (iB < NCENTER) ? center_h + (iB >> 3) * 128
                                         : raw_neighbors + (iB - NCENTER) * 128;

        float4 aA = bv, aB = bv;
        #pragma unroll 8
        for (int d = 0; d < 128; ++d) {
            const float4 mv = *(const float4*)(Ms + d * 128 + cl);
            const float xa = xA[d];
            const float xb = xB[d];
            aA.x = fmaf(xa, mv.x, aA.x); aA.y = fmaf(xa, mv.y, aA.y);
            aA.z = fmaf(xa, mv.z, aA.z); aA.w = fmaf(xa, mv.w, aA.w);
            aB.x = fmaf(xb, mv.x, aB.x); aB.y = fmaf(xb, mv.y, aB.y);
            aB.z = fmaf(xb, mv.z, aB.z); aB.w = fmaf(xb, mv.w, aB.w);
        }

        const bool okA = (g * 4 + 2 * half)     < m;
        const bool okB = (g * 4 + 2 * half + 1) < m;
        if (okA) {
            float4 r;
            r.x = gelu_f(aA.x); r.y = gelu_f(aA.y); r.z = gelu_f(aA.z); r.w = gelu_f(aA.w);
            out4[iA * 32 + (lane & 31)] = r;
        }
        if (okB) {
            float4 r;
            r.x = gelu_f(aB.x); r.y = gelu_f(aB.y); r.z = gelu_f(aB.z); r.w = gelu_f(aB.w);
            out4[iB * 32 + (lane & 31)] = r;
        }
    }
}

extern "C" void kernel_launch(void* const* d_in, const int* in_sizes, int n_in,
                              void* d_out, int out_size, void* d_ws, size_t ws_size,
                              hipStream_t stream) {
    const float* center_h      = (const float*)d_in[0];
    const float* raw_neighbors = (const float*)d_in[1];
    const float* M             = (const float*)d_in[2];
    const float* bias          = (const float*)d_in[3];
    const int*   center_o      = (const int*)d_in[4];
    const int*   s_types       = (const int*)d_in[5];
    const int*   o_types       = (const int*)d_in[6];
    float* out = (float*)d_out;

    fused_kernel<<<dim3(NPAIR * 8), dim3(256), 0, stream>>>(
        center_h, raw_neighbors, M, bias, center_o, s_types, o_types, out);
}